// Round 8
// baseline (2607.347 us; speedup 1.0000x reference)
//
#include <hip/hip_runtime.h>
#include <hip/hip_bf16.h>
#include <math.h>

#define S_LEN  1024
#define DMODEL 5120
#define QLORA  1536
#define KVLORA 512
#define ROPE_D 64
#define NOPE_D 128
#define VDIM_D 128
#define QHEAD  192
#define NHEAD  128

typedef __hip_bfloat16 bf16;

using bf16x8 = __attribute__((ext_vector_type(8))) __bf16;
using f32x4  = __attribute__((ext_vector_type(4))) float;

__device__ __forceinline__ float toF(float x) { return x; }
__device__ __forceinline__ float toF(bf16 x)  { return __bfloat162float(x); }

__device__ __forceinline__ bf16x8 ld8(const bf16* p) {
  return *reinterpret_cast<const bf16x8*>(p);
}

// ---------------------------------------------------------------------------
// f32 -> bf16 bulk convert (vectorized float4 loads).
// ---------------------------------------------------------------------------
__global__ __launch_bounds__(256) void cvt_bf16(const float* __restrict__ in,
                                                bf16* __restrict__ out) {
  const int i = (blockIdx.x * 256 + threadIdx.x) * 4;
  const float4 v = *reinterpret_cast<const float4*>(in + i);
  out[i + 0] = __float2bfloat16(v.x);
  out[i + 1] = __float2bfloat16(v.y);
  out[i + 2] = __float2bfloat16(v.z);
  out[i + 3] = __float2bfloat16(v.w);
}

// ---------------------------------------------------------------------------
// Per-head transpose + f32->bf16:  in (H, R, C) f32  ->  out (H, C, R) bf16.
// ---------------------------------------------------------------------------
__global__ __launch_bounds__(256) void transpose_w(const float* __restrict__ in,
                                                   bf16* __restrict__ out,
                                                   int R, int C) {
  __shared__ float tile[32][33];
  const int h = blockIdx.z;
  const int c0 = blockIdx.x * 32, r0 = blockIdx.y * 32;
  const int rr = threadIdx.x >> 3, cc = (threadIdx.x & 7) * 4;
  const float* ip = in + ((size_t)h * R + r0 + rr) * C + c0 + cc;
#pragma unroll
  for (int i = 0; i < 4; ++i) tile[rr][cc + i] = ip[i];
  __syncthreads();
  bf16* op = out + ((size_t)h * C + c0 + rr) * R + r0 + cc;
#pragma unroll
  for (int i = 0; i < 4; ++i) op[i] = __float2bfloat16(tile[cc + i][rr]);
}

// ---------------------------------------------------------------------------
// MFMA GEMM: C = A(MxK) @ BT^T (BT: N x K), bf16 in, fp32 accumulate.
// 128x128 tile, BK=64, 4 waves (64x64 quadrant each). LDS rows padded to 72.
// SPLIT-K via blockIdx.z. MODE 0: f32 C; MODE 1: bf16 C; MODE 2: bf16 C in
// (H,S,192) head-major; MODE 3: f32 partials at Cout + z*M*N.
// ---------------------------------------------------------------------------
template<int MODE, int SPLIT = 1>
__global__ __launch_bounds__(256) void gemm_mfma(const bf16* __restrict__ A,
                                                 const bf16* __restrict__ BT,
                                                 void* __restrict__ Cout,
                                                 int M, int N, int K) {
  __shared__ bf16 As[128][72];
  __shared__ bf16 Bs[128][72];
  const int n0 = blockIdx.x * 128, m0 = blockIdx.y * 128;
  const int z  = (SPLIT > 1) ? blockIdx.z : 0;
  const int Ks = K / SPLIT;
  const int kbeg = z * Ks;
  const int tid = threadIdx.x;
  const int w = tid >> 6, l = tid & 63, lr = l & 15, lg = l >> 4;
  const int wr = w >> 1, wc = w & 1;

  f32x4 acc[4][4];
#pragma unroll
  for (int x = 0; x < 4; ++x)
#pragma unroll
    for (int y = 0; y < 4; ++y) acc[x][y] = (f32x4){0.f, 0.f, 0.f, 0.f};

  for (int kk = kbeg; kk < kbeg + Ks; kk += 64) {
#pragma unroll
    for (int i = 0; i < 4; ++i) {
      const int e = tid + 256 * i;
      const int r = e >> 3, k8 = (e & 7) * 8;
      *reinterpret_cast<bf16x8*>(&As[r][k8]) =
          ld8(A + (size_t)(m0 + r) * K + kk + k8);
      const int bn = (n0 + r < N) ? n0 + r : N - 1;
      *reinterpret_cast<bf16x8*>(&Bs[r][k8]) =
          ld8(BT + (size_t)bn * K + kk + k8);
    }
    __syncthreads();
#pragma unroll
    for (int kh = 0; kh < 2; ++kh) {
      bf16x8 af[4], bg[4];
#pragma unroll
      for (int x = 0; x < 4; ++x) af[x] = ld8(&As[wr * 64 + x * 16 + lr][kh * 32 + lg * 8]);
#pragma unroll
      for (int y = 0; y < 4; ++y) bg[y] = ld8(&Bs[wc * 64 + y * 16 + lr][kh * 32 + lg * 8]);
#pragma unroll
      for (int x = 0; x < 4; ++x)
#pragma unroll
        for (int y = 0; y < 4; ++y)
          acc[x][y] = __builtin_amdgcn_mfma_f32_16x16x32_bf16(af[x], bg[y], acc[x][y], 0, 0, 0);
    }
    __syncthreads();
  }

#pragma unroll
  for (int x = 0; x < 4; ++x) {
    const int mb = m0 + wr * 64 + x * 16 + lg * 4;
#pragma unroll
    for (int y = 0; y < 4; ++y) {
      const int n = n0 + wc * 64 + y * 16 + lr;
      if (n < N) {
#pragma unroll
        for (int i = 0; i < 4; ++i) {
          const int m = mb + i;
          if (MODE == 0) {
            ((float*)Cout)[(size_t)m * N + n] = acc[x][y][i];
          } else if (MODE == 1) {
            ((bf16*)Cout)[(size_t)m * N + n] = __float2bfloat16(acc[x][y][i]);
          } else if (MODE == 2) {
            const int h = n / QHEAD, j = n - h * QHEAD;
            ((bf16*)Cout)[((size_t)h * S_LEN + m) * QHEAD + j] = __float2bfloat16(acc[x][y][i]);
          } else {
            ((float*)Cout)[(size_t)z * M * N + (size_t)m * N + n] = acc[x][y][i];
          }
        }
      }
    }
  }
}

// ---------------------------------------------------------------------------
// Fused 8-way split-K reduce + RMSNorm: part [8][S][QLORA] f32 -> bf16 out.
// ---------------------------------------------------------------------------
__global__ __launch_bounds__(256) void rmsnorm_fused(const float* __restrict__ part,
                                                     const float* __restrict__ w,
                                                     bf16* __restrict__ out) {
  const int row = blockIdx.x, tid = threadIdx.x;
  __shared__ float red[256];
  float x[6];
  float ss = 0.f;
#pragma unroll
  for (int j = 0; j < 6; ++j) {
    const int c = tid + 256 * j;
    float s = 0.f;
#pragma unroll
    for (int z = 0; z < 8; ++z) s += part[((size_t)z * S_LEN + row) * QLORA + c];
    x[j] = s; ss += s * s;
  }
  red[tid] = ss; __syncthreads();
  for (int t = 128; t > 0; t >>= 1) { if (tid < t) red[tid] += red[tid + t]; __syncthreads(); }
  const float rs = rsqrtf(red[0] / (float)QLORA + 1e-6f);
#pragma unroll
  for (int j = 0; j < 6; ++j) {
    const int c = tid + 256 * j;
    out[(size_t)row * QLORA + c] = __float2bfloat16(x[j] * rs * w[c]);
  }
}

// ---------------------------------------------------------------------------
// Fused 16-way split-K reduce + k_full build.
// ---------------------------------------------------------------------------
__global__ __launch_bounds__(256) void kfull_fused(const float* __restrict__ part,
                                                   const float* __restrict__ w,
                                                   const float* __restrict__ cosb,
                                                   const float* __restrict__ sinb,
                                                   bf16* __restrict__ kfull) {
  const int s = blockIdx.x, tid = threadIdx.x;
  __shared__ float red[256];
  float x0 = 0.f, x1 = 0.f;
#pragma unroll
  for (int z = 0; z < 16; ++z) {
    const float* row = part + ((size_t)z * S_LEN + s) * 576;
    x0 += row[tid]; x1 += row[256 + tid];
  }
  red[tid] = x0 * x0 + x1 * x1; __syncthreads();
  for (int t = 128; t > 0; t >>= 1) { if (tid < t) red[tid] += red[tid + t]; __syncthreads(); }
  const float rs = rsqrtf(red[0] / 512.f + 1e-6f);
  bf16* krow = kfull + (size_t)s * 576;
  krow[tid]       = __float2bfloat16(x0 * rs * w[tid]);
  krow[256 + tid] = __float2bfloat16(x1 * rs * w[256 + tid]);
  if (tid < 32) {
    const int j = tid;
    float a = 0.f, b = 0.f;
#pragma unroll
    for (int z = 0; z < 16; ++z) {
      const float* row = part + ((size_t)z * S_LEN + s) * 576;
      a += row[512 + j]; b += row[544 + j];
    }
    const float* cs = cosb + (size_t)s * 64;
    const float* sn = sinb + (size_t)s * 64;
    krow[512 + j] = __float2bfloat16(a * cs[j] - b * sn[j]);
    krow[544 + j] = __float2bfloat16(b * cs[32 + j] + a * sn[32 + j]);
  }
}

// ---------------------------------------------------------------------------
// 2-way split-K reduce for o-proj: out = p[0] + p[1]  (f32, 1024x5120).
// ---------------------------------------------------------------------------
__global__ __launch_bounds__(256) void reduce2_f32(const float* __restrict__ p,
                                                   float* __restrict__ out) {
  const size_t i = ((size_t)blockIdx.x * 256 + threadIdx.x) * 4;
  const float4 a = *reinterpret_cast<const float4*>(p + i);
  const float4 b = *reinterpret_cast<const float4*>(p + (size_t)S_LEN * DMODEL + i);
  float4 r; r.x = a.x + b.x; r.y = a.y + b.y; r.z = a.z + b.z; r.w = a.w + b.w;
  *reinterpret_cast<float4*>(out + i) = r;
}

// ---------------------------------------------------------------------------
// RoPE on q_pe in-place in q_perm (H, S, 192) layout.
// ---------------------------------------------------------------------------
__global__ __launch_bounds__(256) void rope_q_kernel(bf16* __restrict__ qperm,
                                                     const float* __restrict__ cosb,
                                                     const float* __restrict__ sinb) {
  const int idx = blockIdx.x * 256 + threadIdx.x;   // H*S*32 total
  const int h = idx >> 15;
  const int rem = idx & 32767;
  const int s = rem >> 5;
  const int j = rem & 31;
  bf16* base = qperm + ((size_t)h * S_LEN + s) * QHEAD + NOPE_D;
  const float a = toF(base[j]), b = toF(base[32 + j]);
  const float* cs = cosb + (size_t)s * 64;
  const float* sn = sinb + (size_t)s * 64;
  base[j]      = __float2bfloat16(a * cs[j] - b * sn[j]);
  base[32 + j] = __float2bfloat16(b * cs[32 + j] + a * sn[32 + j]);
}

// ---------------------------------------------------------------------------
// latT (512 x 1024 bf16): latT[v][s] = kfull[s][v] (latent part only).
// ---------------------------------------------------------------------------
__global__ __launch_bounds__(256) void latT_kernel(const bf16* __restrict__ kfull,
                                                   bf16* __restrict__ latT) {
  const int gid = blockIdx.x * 256 + threadIdx.x;   // v*1024 + s
  const int v = gid >> 10, s = gid & 1023;
  latT[gid] = kfull[(size_t)s * 576 + v];
}

// ---------------------------------------------------------------------------
// Fused MLA flash attention. R8: SMALL-BLOCK variant for occupancy.
// Block = 128 threads (2 waves), QB = 16 q-rows, grid = H * S/16 = 8192.
// LDS = 22.5 KB -> 6-7 blocks/CU (vs 2-3 at 54 KB), barriers sync only 2
// waves. Wave w owns score keys [k0+w*16,+16), v-cols [w*256,+256), and
// out cols [w*64,+64). 32-key K-tiles, 2 barriers per tile.
// XCD swizzle: blocks of head h share blockIdx%8 -> same XCD L2 (kcT/vcT).
// ---------------------------------------------------------------------------
#define QB 16
__global__ __launch_bounds__(128, 3) void attn_mfma(const bf16* __restrict__ qperm,
                                                    const bf16* __restrict__ kfull,
                                                    const bf16* __restrict__ kcT,
                                                    const bf16* __restrict__ vcT,
                                                    const bf16* __restrict__ latT,
                                                    bf16* __restrict__ attnv,
                                                    float scale) {
  const int bi = blockIdx.x;            // 0..8191
  const int y  = bi >> 3;               // 0..1023
  const int h  = (bi & 7) * 16 + (y >> 6);
  const int qb = y & 63;
  const int r0 = qb * QB;
  const int tid = threadIdx.x;          // 0..127
  const int w = tid >> 6, l = tid & 63, lr = l & 15, lg = l >> 4;

  __shared__ bf16  Qf[QB][584];         // q_full / O staging, 18688 B
  __shared__ float St[QB][36];          // scores f32, 2304 B
  __shared__ bf16  Pt[QB][40];          // probs bf16, 1280 B
  __shared__ float mrow[QB], lrow[QB], arow[QB];

  // ---- stage roped q_pe into Qf[:,512:576] ----
  for (int e = tid; e < QB * 64; e += 128) {
    const int i = e >> 6, j = e & 63;
    Qf[i][512 + j] = qperm[((size_t)h * S_LEN + r0 + i) * QHEAD + NOPE_D + j];
  }
  // ---- q_abs = q_nope(16x128) @ kc_w[h](128x512); wave w -> cols [w*256,+256) ----
  {
    bf16x8 qn[4];
    const bf16* qp = qperm + ((size_t)h * S_LEN + r0 + lr) * QHEAD;
#pragma unroll
    for (int t = 0; t < 4; ++t) qn[t] = ld8(qp + t * 32 + lg * 8);
#pragma unroll
    for (int ff = 0; ff < 4; ++ff) {
      bf16x8 kb[4][4];
#pragma unroll
      for (int f4 = 0; f4 < 4; ++f4) {
        const int col = w * 256 + (ff * 4 + f4) * 16 + lr;
        const bf16* kp = kcT + ((size_t)h * 512 + col) * 128 + lg * 8;
#pragma unroll
        for (int t = 0; t < 4; ++t) kb[f4][t] = ld8(kp + t * 32);
      }
#pragma unroll
      for (int f4 = 0; f4 < 4; ++f4) {
        f32x4 a0 = {0.f, 0.f, 0.f, 0.f};
        const int col = w * 256 + (ff * 4 + f4) * 16 + lr;
#pragma unroll
        for (int t = 0; t < 4; ++t)
          a0 = __builtin_amdgcn_mfma_f32_16x16x32_bf16(qn[t], kb[f4][t], a0, 0, 0, 0);
#pragma unroll
        for (int i = 0; i < 4; ++i)
          Qf[lg * 4 + i][col] = __float2bfloat16(a0[i]);
      }
    }
  }
  if (tid < QB) { mrow[tid] = -INFINITY; lrow[tid] = 0.f; }
  __syncthreads();

  f32x4 o[16];
#pragma unroll
  for (int f = 0; f < 16; ++f) o[f] = (f32x4){0.f, 0.f, 0.f, 0.f};

  const int kend = r0 + QB;
  for (int k0 = 0; k0 < kend; k0 += 32) {
    // ---- phase A: scores; wave w owns keys [k0+w*16,+16) ----
    {
      const int key = k0 + w * 16 + lr;
      const bf16* kp = kfull + (size_t)key * 576 + lg * 8;
      bf16x8 bb[18];
#pragma unroll
      for (int t = 0; t < 18; ++t) bb[t] = ld8(kp + t * 32);
      f32x4 s0 = {0.f, 0.f, 0.f, 0.f};
      __builtin_amdgcn_s_setprio(1);
#pragma unroll
      for (int t = 0; t < 18; ++t)
        s0 = __builtin_amdgcn_mfma_f32_16x16x32_bf16(ld8(&Qf[lr][t * 32 + lg * 8]), bb[t], s0, 0, 0, 0);
      __builtin_amdgcn_s_setprio(0);
#pragma unroll
      for (int i = 0; i < 4; ++i) {
        const int q0 = r0 + lg * 4 + i;
        St[lg * 4 + i][w * 16 + lr] = (key <= q0) ? s0[i] * scale : -INFINITY;
      }
    }
    __syncthreads();
    // ---- phase B: online softmax; 8 threads per row (4 cols each) ----
    {
      const int r = tid >> 3, seg = tid & 7;
      const float4 sv = *reinterpret_cast<const float4*>(&St[r][seg * 4]);
      float mx = fmaxf(fmaxf(sv.x, sv.y), fmaxf(sv.z, sv.w));
#pragma unroll
      for (int m = 1; m < 8; m <<= 1) mx = fmaxf(mx, __shfl_xor(mx, m, 64));
      const float mold = mrow[r];
      const float mnew = fmaxf(mold, mx);
      const float p0 = expf(sv.x - mnew), p1 = expf(sv.y - mnew);
      const float p2 = expf(sv.z - mnew), p3 = expf(sv.w - mnew);
      Pt[r][seg * 4 + 0] = __float2bfloat16(p0);
      Pt[r][seg * 4 + 1] = __float2bfloat16(p1);
      Pt[r][seg * 4 + 2] = __float2bfloat16(p2);
      Pt[r][seg * 4 + 3] = __float2bfloat16(p3);
      float sum = p0 + p1 + p2 + p3;
#pragma unroll
      for (int m = 1; m < 8; m <<= 1) sum += __shfl_xor(sum, m, 64);
      if (seg == 0) {
        const float alpha = expf(mold - mnew);
        lrow[r] = lrow[r] * alpha + sum;
        mrow[r] = mnew;
        arow[r] = alpha;
      }
    }
    __syncthreads();
    // ---- phase C: O = O*alpha + P @ latent; wave w -> v-cols [w*256,+256) ----
    // (no trailing barrier: next A writes only St; the A->B barrier of the
    //  next iteration orders this phase's Pt reads vs the next Pt writes)
    {
      float al[4];
#pragma unroll
      for (int i = 0; i < 4; ++i) al[i] = arow[lg * 4 + i];
#pragma unroll
      for (int f = 0; f < 16; ++f)
#pragma unroll
        for (int i = 0; i < 4; ++i) o[f][i] *= al[i];
      const bf16x8 pa = ld8(&Pt[lr][lg * 8]);
      __builtin_amdgcn_s_setprio(1);
#pragma unroll
      for (int f = 0; f < 16; ++f) {
        const int v = w * 256 + f * 16 + lr;
        o[f] = __builtin_amdgcn_mfma_f32_16x16x32_bf16(
            pa, ld8(latT + (size_t)v * S_LEN + k0 + lg * 8), o[f], 0, 0, 0);
      }
      __builtin_amdgcn_s_setprio(0);
    }
  }

  // ---- normalize, park O (bf16) in Qf[:, 0:512] ----
  // safe: other wave's phase C touches only Pt/latT/registers, never Qf
  {
    float li[4];
#pragma unroll
    for (int i = 0; i < 4; ++i) li[i] = 1.f / lrow[lg * 4 + i];
#pragma unroll
    for (int f = 0; f < 16; ++f) {
      const int v = w * 256 + f * 16 + lr;
#pragma unroll
      for (int i = 0; i < 4; ++i)
        Qf[lg * 4 + i][v] = __float2bfloat16(o[f][i] * li[i]);
    }
  }
  __syncthreads();
  // ---- attn_v = O(16x512) @ vc_w[h](512x128); wave w -> out cols [w*64,+64) ----
#pragma unroll
  for (int cf = 0; cf < 4; ++cf) {
    const int c = w * 64 + cf * 16 + lr;
    const bf16* vp = vcT + ((size_t)h * 128 + c) * 512 + lg * 8;
    bf16x8 vb[16];
#pragma unroll
    for (int kt = 0; kt < 16; ++kt) vb[kt] = ld8(vp + kt * 32);
    f32x4 acc0 = {0.f, 0.f, 0.f, 0.f};
#pragma unroll
    for (int kt = 0; kt < 16; ++kt)
      acc0 = __builtin_amdgcn_mfma_f32_16x16x32_bf16(ld8(&Qf[lr][kt * 32 + lg * 8]), vb[kt], acc0, 0, 0, 0);
#pragma unroll
    for (int i = 0; i < 4; ++i)
      attnv[(size_t)(r0 + lg * 4 + i) * (NHEAD * VDIM_D) + h * VDIM_D + c] = __float2bfloat16(acc0[i]);
  }
}

// ---------------------------------------------------------------------------
extern "C" void kernel_launch(void* const* d_in, const int* in_sizes, int n_in,
                              void* d_out, int out_size, void* d_ws, size_t ws_size,
                              hipStream_t stream) {
  const float* hidden    = (const float*)d_in[0];
  const float* cosb      = (const float*)d_in[1];
  const float* sinb      = (const float*)d_in[2];
  const float* q_a_w     = (const float*)d_in[3];
  const float* q_a_ln_w  = (const float*)d_in[4];
  const float* q_b_w     = (const float*)d_in[5];
  const float* kv_a_w    = (const float*)d_in[6];
  const float* kv_a_ln_w = (const float*)d_in[7];
  const float* kc_w      = (const float*)d_in[8];
  const float* vc_w      = (const float*)d_in[9];
  const float* o_w       = (const float*)d_in[10];
  float* out = (float*)d_out;

  // workspace layout (bytes), lifetime-overlapped; total 243,269,632 (~232 MiB).
  char* ws = (char*)d_ws;
  bf16*  attnv   = (bf16*)(ws + 0);            // 1024x16384 bf16  33,554,432
  bf16*  kcT     = (bf16*)(ws + 33554432);     // (H,512,128)bf16  16,777,216
  bf16*  vcT     = (bf16*)(ws + 50331648);     // (H,128,512)bf16  16,777,216
  bf16*  kfull   = (bf16*)(ws + 67108864);     // 1024x576   bf16   1,179,648
  bf16*  latT    = (bf16*)(ws + 68288512);     // 512x1024   bf16   1,048,576
  bf16*  qan     = (bf16*)(ws + 69337088);     // 1024x1536  bf16   3,145,728
  bf16*  hb      = (bf16*)(ws + 72482816);     // 1024x5120  bf16  10,485,760
  bf16*  qaT     = (bf16*)(ws + 82968576);     // 1536x5120  bf16  15,728,640
  bf16*  kvaT    = (bf16*)(ws + 98697216);     // 576x5120   bf16   5,898,240
  bf16*  qperm   = (bf16*)(ws + 104595456);    // (H,S,192)  bf16  50,331,648
  float* qa_part = (float*)(ws + 104595456);   // [8][1024][1536] f32 50,331,648 (pre-qperm)
  bf16*  qbT     = (bf16*)(ws + 154927104);    // 24576x1536 bf16  75,497,472
  float* kv_part = (float*)(ws + 154927104);   // [16][1024][576] f32 37,748,736 (post-q_b)
  float* o_part  = (float*)(ws + 33554432);    // [2][1024][5120] f32 41,943,040 (post-attn)
  bf16*  owT     = (bf16*)(ws + 75497472);     // 5120x16384 bf16 167,772,160 (post-attn)

  const double msc = 0.1 * log(40.0) + 1.0;
  const float scale = (float)(pow((double)QHEAD, -0.5) * msc * msc);

  // hidden -> bf16
  cvt_bf16<<<(S_LEN * DMODEL) / 1024, 256, 0, stream>>>(hidden, hb);
  // weight transposes -> bf16
  transpose_w<<<dim3(QLORA / 32, DMODEL / 32, 1), 256, 0, stream>>>(q_a_w, qaT, DMODEL, QLORA);
  transpose_w<<<dim3(576 / 32, DMODEL / 32, 1), 256, 0, stream>>>(kv_a_w, kvaT, DMODEL, 576);
  transpose_w<<<dim3((NHEAD * QHEAD) / 32, QLORA / 32, 1), 256, 0, stream>>>(q_b_w, qbT, QLORA, NHEAD * QHEAD);
  transpose_w<<<dim3(512 / 32, 128 / 32, NHEAD), 256, 0, stream>>>(kc_w, kcT, 128, 512);
  transpose_w<<<dim3(128 / 32, 512 / 32, NHEAD), 256, 0, stream>>>(vc_w, vcT, 512, 128);

  // q_a: (1024x5120)@(5120x1536), split-K 8 -> qa_part
  gemm_mfma<3, 8><<<dim3(QLORA / 128, S_LEN / 128, 8), 256, 0, stream>>>(
      hb, qaT, qa_part, S_LEN, QLORA, DMODEL);
  // fused reduce + rmsnorm -> qan
  rmsnorm_fused<<<S_LEN, 256, 0, stream>>>(qa_part, q_a_ln_w, qan);
  // q_b: (1024x1536)@(1536x24576) -> qperm (head-major)
  gemm_mfma<2><<<dim3((NHEAD * QHEAD) / 128, S_LEN / 128), 256, 0, stream>>>(
      qan, qbT, qperm, S_LEN, NHEAD * QHEAD, QLORA);
  // kv_a: (1024x5120)@(5120x576), split-K 16 -> kv_part
  gemm_mfma<3, 16><<<dim3(5, S_LEN / 128, 16), 256, 0, stream>>>(
      hb, kvaT, kv_part, S_LEN, KVLORA + ROPE_D, DMODEL);
  // fused reduce + k_full build
  kfull_fused<<<S_LEN, 256, 0, stream>>>(kv_part, kv_a_ln_w, cosb, sinb, kfull);
  // latent transpose for PV B-operands
  latT_kernel<<<(KVLORA * S_LEN) / 256, 256, 0, stream>>>(kfull, latT);
  // rope q_pe in place
  rope_q_kernel<<<(NHEAD * S_LEN * 32) / 256, 256, 0, stream>>>(qperm, cosb, sinb);
  // fused MFMA attention: 8192 small blocks (2 waves), XCD-swizzled
  attn_mfma<<<dim3(NHEAD * (S_LEN / QB)), 128, 0, stream>>>(
      qperm, kfull, kcT, vcT, latT, attnv, scale);
  // o_w transpose (pre-attn buffers now dead; owT overlaps them)
  transpose_w<<<dim3(DMODEL / 32, (NHEAD * VDIM_D) / 32, 1), 256, 0, stream>>>(
      o_w, owT, NHEAD * VDIM_D, DMODEL);
  // output projection: (1024x16384)@(16384x5120), split-K 2 -> o_part
  gemm_mfma<3, 2><<<dim3(DMODEL / 128, S_LEN / 128, 2), 256, 0, stream>>>(
      attnv, owT, o_part, S_LEN, DMODEL, NHEAD * VDIM_D);
  // final reduce -> out (f32)
  reduce2_f32<<<(S_LEN * DMODEL) / 1024, 256, 0, stream>>>(o_part, out);
}

// Round 9
// 1980.926 us; speedup vs baseline: 1.3162x; 1.3162x over previous
//
#include <hip/hip_runtime.h>
#include <hip/hip_bf16.h>
#include <math.h>

#define S_LEN  1024
#define DMODEL 5120
#define QLORA  1536
#define KVLORA 512
#define ROPE_D 64
#define NOPE_D 128
#define VDIM_D 128
#define QHEAD  192
#define NHEAD  128

typedef __hip_bfloat16 bf16;

using bf16x8 = __attribute__((ext_vector_type(8))) __bf16;
using f32x4  = __attribute__((ext_vector_type(4))) float;

__device__ __forceinline__ float toF(float x) { return x; }
__device__ __forceinline__ float toF(bf16 x)  { return __bfloat162float(x); }

__device__ __forceinline__ bf16x8 ld8(const bf16* p) {
  return *reinterpret_cast<const bf16x8*>(p);
}

// ---------------------------------------------------------------------------
// f32 -> bf16 bulk convert (vectorized float4 loads).
// ---------------------------------------------------------------------------
__global__ __launch_bounds__(256) void cvt_bf16(const float* __restrict__ in,
                                                bf16* __restrict__ out) {
  const int i = (blockIdx.x * 256 + threadIdx.x) * 4;
  const float4 v = *reinterpret_cast<const float4*>(in + i);
  out[i + 0] = __float2bfloat16(v.x);
  out[i + 1] = __float2bfloat16(v.y);
  out[i + 2] = __float2bfloat16(v.z);
  out[i + 3] = __float2bfloat16(v.w);
}

// ---------------------------------------------------------------------------
// zero-fill f32 buffer (float4 stores).
// ---------------------------------------------------------------------------
__global__ __launch_bounds__(256) void zero_f32(float* __restrict__ p) {
  const size_t i = ((size_t)blockIdx.x * 256 + threadIdx.x) * 4;
  *reinterpret_cast<float4*>(p + i) = (float4){0.f, 0.f, 0.f, 0.f};
}

// ---------------------------------------------------------------------------
// Per-head transpose + f32->bf16:  in (H, R, C) f32  ->  out (H, C, R) bf16.
// ---------------------------------------------------------------------------
__global__ __launch_bounds__(256) void transpose_w(const float* __restrict__ in,
                                                   bf16* __restrict__ out,
                                                   int R, int C) {
  __shared__ float tile[32][33];
  const int h = blockIdx.z;
  const int c0 = blockIdx.x * 32, r0 = blockIdx.y * 32;
  const int rr = threadIdx.x >> 3, cc = (threadIdx.x & 7) * 4;
  const float* ip = in + ((size_t)h * R + r0 + rr) * C + c0 + cc;
#pragma unroll
  for (int i = 0; i < 4; ++i) tile[rr][cc + i] = ip[i];
  __syncthreads();
  bf16* op = out + ((size_t)h * C + c0 + rr) * R + r0 + cc;
#pragma unroll
  for (int i = 0; i < 4; ++i) op[i] = __float2bfloat16(tile[cc + i][rr]);
}

// ---------------------------------------------------------------------------
// MFMA GEMM: C = A(MxK) @ BT^T (BT: N x K), bf16 in, fp32 accumulate.
// 128x128 tile, BK=64, 4 waves (64x64 quadrant each). LDS rows padded to 72.
// SPLIT-K via blockIdx.z. MODE 0: f32 C; MODE 1: bf16 C; MODE 2: bf16 C in
// (H,S,192) head-major; MODE 3: f32 partials at Cout + z*M*N; MODE 4: f32
// atomic-add into Cout (global_atomic_add_f32 via unsafeAtomicAdd; requires
// Cout pre-zeroed).
// ---------------------------------------------------------------------------
template<int MODE, int SPLIT = 1>
__global__ __launch_bounds__(256) void gemm_mfma(const bf16* __restrict__ A,
                                                 const bf16* __restrict__ BT,
                                                 void* __restrict__ Cout,
                                                 int M, int N, int K) {
  __shared__ bf16 As[128][72];
  __shared__ bf16 Bs[128][72];
  const int n0 = blockIdx.x * 128, m0 = blockIdx.y * 128;
  const int z  = (SPLIT > 1) ? blockIdx.z : 0;
  const int Ks = K / SPLIT;
  const int kbeg = z * Ks;
  const int tid = threadIdx.x;
  const int w = tid >> 6, l = tid & 63, lr = l & 15, lg = l >> 4;
  const int wr = w >> 1, wc = w & 1;

  f32x4 acc[4][4];
#pragma unroll
  for (int x = 0; x < 4; ++x)
#pragma unroll
    for (int y = 0; y < 4; ++y) acc[x][y] = (f32x4){0.f, 0.f, 0.f, 0.f};

  for (int kk = kbeg; kk < kbeg + Ks; kk += 64) {
#pragma unroll
    for (int i = 0; i < 4; ++i) {
      const int e = tid + 256 * i;
      const int r = e >> 3, k8 = (e & 7) * 8;
      *reinterpret_cast<bf16x8*>(&As[r][k8]) =
          ld8(A + (size_t)(m0 + r) * K + kk + k8);
      const int bn = (n0 + r < N) ? n0 + r : N - 1;
      *reinterpret_cast<bf16x8*>(&Bs[r][k8]) =
          ld8(BT + (size_t)bn * K + kk + k8);
    }
    __syncthreads();
#pragma unroll
    for (int kh = 0; kh < 2; ++kh) {
      bf16x8 af[4], bg[4];
#pragma unroll
      for (int x = 0; x < 4; ++x) af[x] = ld8(&As[wr * 64 + x * 16 + lr][kh * 32 + lg * 8]);
#pragma unroll
      for (int y = 0; y < 4; ++y) bg[y] = ld8(&Bs[wc * 64 + y * 16 + lr][kh * 32 + lg * 8]);
#pragma unroll
      for (int x = 0; x < 4; ++x)
#pragma unroll
        for (int y = 0; y < 4; ++y)
          acc[x][y] = __builtin_amdgcn_mfma_f32_16x16x32_bf16(af[x], bg[y], acc[x][y], 0, 0, 0);
    }
    __syncthreads();
  }

#pragma unroll
  for (int x = 0; x < 4; ++x) {
    const int mb = m0 + wr * 64 + x * 16 + lg * 4;
#pragma unroll
    for (int y = 0; y < 4; ++y) {
      const int n = n0 + wc * 64 + y * 16 + lr;
      if (n < N) {
#pragma unroll
        for (int i = 0; i < 4; ++i) {
          const int m = mb + i;
          if (MODE == 0) {
            ((float*)Cout)[(size_t)m * N + n] = acc[x][y][i];
          } else if (MODE == 1) {
            ((bf16*)Cout)[(size_t)m * N + n] = __float2bfloat16(acc[x][y][i]);
          } else if (MODE == 2) {
            const int h = n / QHEAD, j = n - h * QHEAD;
            ((bf16*)Cout)[((size_t)h * S_LEN + m) * QHEAD + j] = __float2bfloat16(acc[x][y][i]);
          } else if (MODE == 3) {
            ((float*)Cout)[(size_t)z * M * N + (size_t)m * N + n] = acc[x][y][i];
          } else {
            unsafeAtomicAdd(&((float*)Cout)[(size_t)m * N + n], acc[x][y][i]);
          }
        }
      }
    }
  }
}

// ---------------------------------------------------------------------------
// Fused 8-way split-K reduce + RMSNorm: part [8][S][QLORA] f32 -> bf16 out.
// ---------------------------------------------------------------------------
__global__ __launch_bounds__(256) void rmsnorm_fused(const float* __restrict__ part,
                                                     const float* __restrict__ w,
                                                     bf16* __restrict__ out) {
  const int row = blockIdx.x, tid = threadIdx.x;
  __shared__ float red[256];
  float x[6];
  float ss = 0.f;
#pragma unroll
  for (int j = 0; j < 6; ++j) {
    const int c = tid + 256 * j;
    float s = 0.f;
#pragma unroll
    for (int z = 0; z < 8; ++z) s += part[((size_t)z * S_LEN + row) * QLORA + c];
    x[j] = s; ss += s * s;
  }
  red[tid] = ss; __syncthreads();
  for (int t = 128; t > 0; t >>= 1) { if (tid < t) red[tid] += red[tid + t]; __syncthreads(); }
  const float rs = rsqrtf(red[0] / (float)QLORA + 1e-6f);
#pragma unroll
  for (int j = 0; j < 6; ++j) {
    const int c = tid + 256 * j;
    out[(size_t)row * QLORA + c] = __float2bfloat16(x[j] * rs * w[c]);
  }
}

// ---------------------------------------------------------------------------
// Fused 16-way split-K reduce + k_full build.
// ---------------------------------------------------------------------------
__global__ __launch_bounds__(256) void kfull_fused(const float* __restrict__ part,
                                                   const float* __restrict__ w,
                                                   const float* __restrict__ cosb,
                                                   const float* __restrict__ sinb,
                                                   bf16* __restrict__ kfull) {
  const int s = blockIdx.x, tid = threadIdx.x;
  __shared__ float red[256];
  float x0 = 0.f, x1 = 0.f;
#pragma unroll
  for (int z = 0; z < 16; ++z) {
    const float* row = part + ((size_t)z * S_LEN + s) * 576;
    x0 += row[tid]; x1 += row[256 + tid];
  }
  red[tid] = x0 * x0 + x1 * x1; __syncthreads();
  for (int t = 128; t > 0; t >>= 1) { if (tid < t) red[tid] += red[tid + t]; __syncthreads(); }
  const float rs = rsqrtf(red[0] / 512.f + 1e-6f);
  bf16* krow = kfull + (size_t)s * 576;
  krow[tid]       = __float2bfloat16(x0 * rs * w[tid]);
  krow[256 + tid] = __float2bfloat16(x1 * rs * w[256 + tid]);
  if (tid < 32) {
    const int j = tid;
    float a = 0.f, b = 0.f;
#pragma unroll
    for (int z = 0; z < 16; ++z) {
      const float* row = part + ((size_t)z * S_LEN + s) * 576;
      a += row[512 + j]; b += row[544 + j];
    }
    const float* cs = cosb + (size_t)s * 64;
    const float* sn = sinb + (size_t)s * 64;
    krow[512 + j] = __float2bfloat16(a * cs[j] - b * sn[j]);
    krow[544 + j] = __float2bfloat16(b * cs[32 + j] + a * sn[32 + j]);
  }
}

// ---------------------------------------------------------------------------
// RoPE on q_pe in-place in q_perm (H, S, 192) layout.
// ---------------------------------------------------------------------------
__global__ __launch_bounds__(256) void rope_q_kernel(bf16* __restrict__ qperm,
                                                     const float* __restrict__ cosb,
                                                     const float* __restrict__ sinb) {
  const int idx = blockIdx.x * 256 + threadIdx.x;   // H*S*32 total
  const int h = idx >> 15;
  const int rem = idx & 32767;
  const int s = rem >> 5;
  const int j = rem & 31;
  bf16* base = qperm + ((size_t)h * S_LEN + s) * QHEAD + NOPE_D;
  const float a = toF(base[j]), b = toF(base[32 + j]);
  const float* cs = cosb + (size_t)s * 64;
  const float* sn = sinb + (size_t)s * 64;
  base[j]      = __float2bfloat16(a * cs[j] - b * sn[j]);
  base[32 + j] = __float2bfloat16(b * cs[32 + j] + a * sn[32 + j]);
}

// ---------------------------------------------------------------------------
// latT (512 x 1024 bf16): latT[v][s] = kfull[s][v] (latent part only).
// ---------------------------------------------------------------------------
__global__ __launch_bounds__(256) void latT_kernel(const bf16* __restrict__ kfull,
                                                   bf16* __restrict__ latT) {
  const int gid = blockIdx.x * 256 + threadIdx.x;   // v*1024 + s
  const int v = gid >> 10, s = gid & 1023;
  latT[gid] = kfull[(size_t)s * 576 + v];
}

// ---------------------------------------------------------------------------
// Fused MLA flash attention (R6-exact: best measured variant, 828 us).
// MFMA, QB=32, 256 threads / 4 waves, XCD-aware swizzle, batch-issued
// B-operand register loads, s_setprio around MFMA clusters.
// ---------------------------------------------------------------------------
#define QB 32
__global__ __launch_bounds__(256, 3) void attn_mfma(const bf16* __restrict__ qperm,
                                                    const bf16* __restrict__ kfull,
                                                    const bf16* __restrict__ kcT,
                                                    const bf16* __restrict__ vcT,
                                                    const bf16* __restrict__ latT,
                                                    bf16* __restrict__ attnv,
                                                    float scale) {
  const int bi = blockIdx.x;            // 0..4095
  const int y  = bi >> 3;               // 0..511
  const int h  = (bi & 7) * 16 + (y >> 5);
  const int qb = y & 31;
  const int r0 = qb * QB;
  const int tid = threadIdx.x;
  const int w = tid >> 6, l = tid & 63, lr = l & 15, lg = l >> 4;

  __shared__ bf16  Qf[QB][584];
  __shared__ float St[QB][68];
  __shared__ bf16  Pt[QB][72];
  __shared__ float mrow[QB], lrow[QB], arow[QB];

  for (int e = tid; e < QB * 64; e += 256) {
    const int i = e >> 6, j = e & 63;
    Qf[i][512 + j] = qperm[((size_t)h * S_LEN + r0 + i) * QHEAD + NOPE_D + j];
  }
  {
    bf16x8 qn[2][4];
#pragma unroll
    for (int x = 0; x < 2; ++x) {
      const bf16* qp = qperm + ((size_t)h * S_LEN + r0 + x * 16 + lr) * QHEAD;
#pragma unroll
      for (int t = 0; t < 4; ++t) qn[x][t] = ld8(qp + t * 32 + lg * 8);
    }
#pragma unroll
    for (int ff = 0; ff < 2; ++ff) {
      bf16x8 kb[4][4];
#pragma unroll
      for (int f4 = 0; f4 < 4; ++f4) {
        const int col = w * 128 + (ff * 4 + f4) * 16 + lr;
        const bf16* kp = kcT + ((size_t)h * 512 + col) * 128 + lg * 8;
#pragma unroll
        for (int t = 0; t < 4; ++t) kb[f4][t] = ld8(kp + t * 32);
      }
#pragma unroll
      for (int f4 = 0; f4 < 4; ++f4) {
        f32x4 a0 = {0.f, 0.f, 0.f, 0.f}, a1 = {0.f, 0.f, 0.f, 0.f};
        const int col = w * 128 + (ff * 4 + f4) * 16 + lr;
#pragma unroll
        for (int t = 0; t < 4; ++t) {
          a0 = __builtin_amdgcn_mfma_f32_16x16x32_bf16(qn[0][t], kb[f4][t], a0, 0, 0, 0);
          a1 = __builtin_amdgcn_mfma_f32_16x16x32_bf16(qn[1][t], kb[f4][t], a1, 0, 0, 0);
        }
#pragma unroll
        for (int i = 0; i < 4; ++i) {
          Qf[lg * 4 + i][col]      = __float2bfloat16(a0[i]);
          Qf[16 + lg * 4 + i][col] = __float2bfloat16(a1[i]);
        }
      }
    }
  }
  if (tid < QB) { mrow[tid] = -INFINITY; lrow[tid] = 0.f; }
  __syncthreads();

  f32x4 o[2][8];
#pragma unroll
  for (int x = 0; x < 2; ++x)
#pragma unroll
    for (int f = 0; f < 8; ++f) o[x][f] = (f32x4){0.f, 0.f, 0.f, 0.f};

  const int kend = r0 + QB;
  for (int k0 = 0; k0 < kend; k0 += 64) {
    {
      const int key = k0 + w * 16 + lr;
      const bf16* kp = kfull + (size_t)key * 576 + lg * 8;
      bf16x8 bb[18];
#pragma unroll
      for (int t = 0; t < 18; ++t) bb[t] = ld8(kp + t * 32);
      f32x4 s0 = {0.f, 0.f, 0.f, 0.f}, s1 = {0.f, 0.f, 0.f, 0.f};
      __builtin_amdgcn_s_setprio(1);
#pragma unroll
      for (int t = 0; t < 18; ++t) {
        s0 = __builtin_amdgcn_mfma_f32_16x16x32_bf16(ld8(&Qf[lr][t * 32 + lg * 8]), bb[t], s0, 0, 0, 0);
        s1 = __builtin_amdgcn_mfma_f32_16x16x32_bf16(ld8(&Qf[16 + lr][t * 32 + lg * 8]), bb[t], s1, 0, 0, 0);
      }
      __builtin_amdgcn_s_setprio(0);
#pragma unroll
      for (int i = 0; i < 4; ++i) {
        const int q0 = r0 + lg * 4 + i;
        const int q1 = r0 + 16 + lg * 4 + i;
        St[lg * 4 + i][w * 16 + lr]      = (key <= q0) ? s0[i] * scale : -INFINITY;
        St[16 + lg * 4 + i][w * 16 + lr] = (key <= q1) ? s1[i] * scale : -INFINITY;
      }
    }
    __syncthreads();
    {
      const int r = tid >> 3, seg = tid & 7;
      const float4 v0 = *reinterpret_cast<const float4*>(&St[r][seg * 8]);
      const float4 v1 = *reinterpret_cast<const float4*>(&St[r][seg * 8 + 4]);
      float mx = fmaxf(fmaxf(fmaxf(v0.x, v0.y), fmaxf(v0.z, v0.w)),
                       fmaxf(fmaxf(v1.x, v1.y), fmaxf(v1.z, v1.w)));
#pragma unroll
      for (int m = 1; m < 8; m <<= 1) mx = fmaxf(mx, __shfl_xor(mx, m, 64));
      const float mold = mrow[r];
      const float mnew = fmaxf(mold, mx);
      const float p0 = expf(v0.x - mnew), p1 = expf(v0.y - mnew);
      const float p2 = expf(v0.z - mnew), p3 = expf(v0.w - mnew);
      const float p4 = expf(v1.x - mnew), p5 = expf(v1.y - mnew);
      const float p6 = expf(v1.z - mnew), p7 = expf(v1.w - mnew);
      Pt[r][seg * 8 + 0] = __float2bfloat16(p0);
      Pt[r][seg * 8 + 1] = __float2bfloat16(p1);
      Pt[r][seg * 8 + 2] = __float2bfloat16(p2);
      Pt[r][seg * 8 + 3] = __float2bfloat16(p3);
      Pt[r][seg * 8 + 4] = __float2bfloat16(p4);
      Pt[r][seg * 8 + 5] = __float2bfloat16(p5);
      Pt[r][seg * 8 + 6] = __float2bfloat16(p6);
      Pt[r][seg * 8 + 7] = __float2bfloat16(p7);
      float sum = p0 + p1 + p2 + p3 + p4 + p5 + p6 + p7;
#pragma unroll
      for (int m = 1; m < 8; m <<= 1) sum += __shfl_xor(sum, m, 64);
      if (seg == 0) {
        const float alpha = expf(mold - mnew);
        lrow[r] = lrow[r] * alpha + sum;
        mrow[r] = mnew;
        arow[r] = alpha;
      }
    }
    __syncthreads();
    {
      bf16x8 bl[16];
#pragma unroll
      for (int f = 0; f < 8; ++f) {
        const int v = w * 128 + f * 16 + lr;
        const bf16* bp = latT + (size_t)v * S_LEN + k0 + lg * 8;
        bl[2 * f]     = ld8(bp);
        bl[2 * f + 1] = ld8(bp + 32);
      }
      float al0[4], al1[4];
#pragma unroll
      for (int i = 0; i < 4; ++i) {
        al0[i] = arow[lg * 4 + i];
        al1[i] = arow[16 + lg * 4 + i];
      }
#pragma unroll
      for (int f = 0; f < 8; ++f)
#pragma unroll
        for (int i = 0; i < 4; ++i) {
          o[0][f][i] *= al0[i];
          o[1][f][i] *= al1[i];
        }
      bf16x8 pa[2][2];
      pa[0][0] = ld8(&Pt[lr][lg * 8]);
      pa[0][1] = ld8(&Pt[lr][32 + lg * 8]);
      pa[1][0] = ld8(&Pt[16 + lr][lg * 8]);
      pa[1][1] = ld8(&Pt[16 + lr][32 + lg * 8]);
      __builtin_amdgcn_s_setprio(1);
#pragma unroll
      for (int f = 0; f < 8; ++f) {
        o[0][f] = __builtin_amdgcn_mfma_f32_16x16x32_bf16(pa[0][0], bl[2 * f],     o[0][f], 0, 0, 0);
        o[0][f] = __builtin_amdgcn_mfma_f32_16x16x32_bf16(pa[0][1], bl[2 * f + 1], o[0][f], 0, 0, 0);
        o[1][f] = __builtin_amdgcn_mfma_f32_16x16x32_bf16(pa[1][0], bl[2 * f],     o[1][f], 0, 0, 0);
        o[1][f] = __builtin_amdgcn_mfma_f32_16x16x32_bf16(pa[1][1], bl[2 * f + 1], o[1][f], 0, 0, 0);
      }
      __builtin_amdgcn_s_setprio(0);
    }
  }

  {
    float li0[4], li1[4];
#pragma unroll
    for (int i = 0; i < 4; ++i) {
      li0[i] = 1.f / lrow[lg * 4 + i];
      li1[i] = 1.f / lrow[16 + lg * 4 + i];
    }
#pragma unroll
    for (int f = 0; f < 8; ++f) {
      const int v = w * 128 + f * 16 + lr;
#pragma unroll
      for (int i = 0; i < 4; ++i) {
        Qf[lg * 4 + i][v]      = __float2bfloat16(o[0][f][i] * li0[i]);
        Qf[16 + lg * 4 + i][v] = __float2bfloat16(o[1][f][i] * li1[i]);
      }
    }
  }
  __syncthreads();
#pragma unroll
  for (int cf = 0; cf < 2; ++cf) {
    const int c = w * 32 + cf * 16 + lr;
    const bf16* vp = vcT + ((size_t)h * 128 + c) * 512 + lg * 8;
    bf16x8 vb[16];
#pragma unroll
    for (int kt = 0; kt < 16; ++kt) vb[kt] = ld8(vp + kt * 32);
    f32x4 acc0 = {0.f, 0.f, 0.f, 0.f}, acc1 = {0.f, 0.f, 0.f, 0.f};
#pragma unroll
    for (int kt = 0; kt < 16; ++kt) {
      acc0 = __builtin_amdgcn_mfma_f32_16x16x32_bf16(ld8(&Qf[lr][kt * 32 + lg * 8]), vb[kt], acc0, 0, 0, 0);
      acc1 = __builtin_amdgcn_mfma_f32_16x16x32_bf16(ld8(&Qf[16 + lr][kt * 32 + lg * 8]), vb[kt], acc1, 0, 0, 0);
    }
#pragma unroll
    for (int i = 0; i < 4; ++i) {
      attnv[(size_t)(r0 + lg * 4 + i) * (NHEAD * VDIM_D) + h * VDIM_D + c]      = __float2bfloat16(acc0[i]);
      attnv[(size_t)(r0 + 16 + lg * 4 + i) * (NHEAD * VDIM_D) + h * VDIM_D + c] = __float2bfloat16(acc1[i]);
    }
  }
}

// ---------------------------------------------------------------------------
extern "C" void kernel_launch(void* const* d_in, const int* in_sizes, int n_in,
                              void* d_out, int out_size, void* d_ws, size_t ws_size,
                              hipStream_t stream) {
  const float* hidden    = (const float*)d_in[0];
  const float* cosb      = (const float*)d_in[1];
  const float* sinb      = (const float*)d_in[2];
  const float* q_a_w     = (const float*)d_in[3];
  const float* q_a_ln_w  = (const float*)d_in[4];
  const float* q_b_w     = (const float*)d_in[5];
  const float* kv_a_w    = (const float*)d_in[6];
  const float* kv_a_ln_w = (const float*)d_in[7];
  const float* kc_w      = (const float*)d_in[8];
  const float* vc_w      = (const float*)d_in[9];
  const float* o_w       = (const float*)d_in[10];
  float* out = (float*)d_out;

  // workspace layout (bytes), lifetime-overlapped; total 243,269,632 (~232 MiB).
  char* ws = (char*)d_ws;
  bf16*  attnv   = (bf16*)(ws + 0);            // 1024x16384 bf16  33,554,432
  bf16*  kcT     = (bf16*)(ws + 33554432);     // (H,512,128)bf16  16,777,216
  bf16*  vcT     = (bf16*)(ws + 50331648);     // (H,128,512)bf16  16,777,216
  bf16*  kfull   = (bf16*)(ws + 67108864);     // 1024x576   bf16   1,179,648
  bf16*  latT    = (bf16*)(ws + 68288512);     // 512x1024   bf16   1,048,576
  bf16*  qan     = (bf16*)(ws + 69337088);     // 1024x1536  bf16   3,145,728
  bf16*  hb      = (bf16*)(ws + 72482816);     // 1024x5120  bf16  10,485,760
  bf16*  qaT     = (bf16*)(ws + 82968576);     // 1536x5120  bf16  15,728,640
  bf16*  kvaT    = (bf16*)(ws + 98697216);     // 576x5120   bf16   5,898,240
  bf16*  qperm   = (bf16*)(ws + 104595456);    // (H,S,192)  bf16  50,331,648
  float* qa_part = (float*)(ws + 104595456);   // [8][1024][1536] f32 50,331,648 (pre-qperm)
  bf16*  qbT     = (bf16*)(ws + 154927104);    // 24576x1536 bf16  75,497,472
  float* kv_part = (float*)(ws + 154927104);   // [16][1024][576] f32 37,748,736 (post-q_b)
  bf16*  owT     = (bf16*)(ws + 75497472);     // 5120x16384 bf16 167,772,160 (post-attn)

  const double msc = 0.1 * log(40.0) + 1.0;
  const float scale = (float)(pow((double)QHEAD, -0.5) * msc * msc);

  // hidden -> bf16
  cvt_bf16<<<(S_LEN * DMODEL) / 1024, 256, 0, stream>>>(hidden, hb);
  // weight transposes -> bf16
  transpose_w<<<dim3(QLORA / 32, DMODEL / 32, 1), 256, 0, stream>>>(q_a_w, qaT, DMODEL, QLORA);
  transpose_w<<<dim3(576 / 32, DMODEL / 32, 1), 256, 0, stream>>>(kv_a_w, kvaT, DMODEL, 576);
  transpose_w<<<dim3((NHEAD * QHEAD) / 32, QLORA / 32, 1), 256, 0, stream>>>(q_b_w, qbT, QLORA, NHEAD * QHEAD);
  transpose_w<<<dim3(512 / 32, 128 / 32, NHEAD), 256, 0, stream>>>(kc_w, kcT, 128, 512);
  transpose_w<<<dim3(128 / 32, 512 / 32, NHEAD), 256, 0, stream>>>(vc_w, vcT, 512, 128);

  // q_a: (1024x5120)@(5120x1536), split-K 8 -> qa_part
  gemm_mfma<3, 8><<<dim3(QLORA / 128, S_LEN / 128, 8), 256, 0, stream>>>(
      hb, qaT, qa_part, S_LEN, QLORA, DMODEL);
  // fused reduce + rmsnorm -> qan
  rmsnorm_fused<<<S_LEN, 256, 0, stream>>>(qa_part, q_a_ln_w, qan);
  // q_b: (1024x1536)@(1536x24576) -> qperm (head-major)
  gemm_mfma<2><<<dim3((NHEAD * QHEAD) / 128, S_LEN / 128), 256, 0, stream>>>(
      qan, qbT, qperm, S_LEN, NHEAD * QHEAD, QLORA);
  // kv_a: (1024x5120)@(5120x576), split-K 16 -> kv_part
  gemm_mfma<3, 16><<<dim3(5, S_LEN / 128, 16), 256, 0, stream>>>(
      hb, kvaT, kv_part, S_LEN, KVLORA + ROPE_D, DMODEL);
  // fused reduce + k_full build
  kfull_fused<<<S_LEN, 256, 0, stream>>>(kv_part, kv_a_ln_w, cosb, sinb, kfull);
  // latent transpose for PV B-operands
  latT_kernel<<<(KVLORA * S_LEN) / 256, 256, 0, stream>>>(kfull, latT);
  // rope q_pe in place
  rope_q_kernel<<<(NHEAD * S_LEN * 32) / 256, 256, 0, stream>>>(qperm, cosb, sinb);
  // fused MFMA attention (q absorb + flash + vc projection), XCD-swizzled
  attn_mfma<<<dim3(NHEAD * (S_LEN / QB)), 256, 0, stream>>>(
      qperm, kfull, kcT, vcT, latT, attnv, scale);
  // o_w transpose (pre-attn buffers now dead; owT overlaps them)
  transpose_w<<<dim3(DMODEL / 32, (NHEAD * VDIM_D) / 32, 1), 256, 0, stream>>>(
      o_w, owT, NHEAD * VDIM_D, DMODEL);
  // zero out, then output projection with split-K 4 atomic accumulation:
  // (1024x16384)@(16384x5120) -> out (f32)
  zero_f32<<<(S_LEN * DMODEL) / 1024, 256, 0, stream>>>(out);
  gemm_mfma<4, 4><<<dim3(DMODEL / 128, S_LEN / 128, 4), 256, 0, stream>>>(
      attnv, owT, out, S_LEN, DMODEL, NHEAD * VDIM_D);
}

// Round 10
// 1949.303 us; speedup vs baseline: 1.3376x; 1.0162x over previous
//
#include <hip/hip_runtime.h>
#include <hip/hip_bf16.h>
#include <math.h>

#define S_LEN  1024
#define DMODEL 5120
#define QLORA  1536
#define KVLORA 512
#define ROPE_D 64
#define NOPE_D 128
#define VDIM_D 128
#define QHEAD  192
#define NHEAD  128

typedef __hip_bfloat16 bf16;

using bf16x8 = __attribute__((ext_vector_type(8))) __bf16;
using f32x4  = __attribute__((ext_vector_type(4))) float;

__device__ __forceinline__ float toF(float x) { return x; }
__device__ __forceinline__ float toF(bf16 x)  { return __bfloat162float(x); }

__device__ __forceinline__ bf16x8 ld8(const bf16* p) {
  return *reinterpret_cast<const bf16x8*>(p);
}

// ---------------------------------------------------------------------------
// f32 -> bf16 bulk convert (vectorized float4 loads).
// ---------------------------------------------------------------------------
__global__ __launch_bounds__(256) void cvt_bf16(const float* __restrict__ in,
                                                bf16* __restrict__ out) {
  const int i = (blockIdx.x * 256 + threadIdx.x) * 4;
  const float4 v = *reinterpret_cast<const float4*>(in + i);
  out[i + 0] = __float2bfloat16(v.x);
  out[i + 1] = __float2bfloat16(v.y);
  out[i + 2] = __float2bfloat16(v.z);
  out[i + 3] = __float2bfloat16(v.w);
}

// ---------------------------------------------------------------------------
// zero-fill f32 buffer (float4 stores).
// ---------------------------------------------------------------------------
__global__ __launch_bounds__(256) void zero_f32(float* __restrict__ p) {
  const size_t i = ((size_t)blockIdx.x * 256 + threadIdx.x) * 4;
  *reinterpret_cast<float4*>(p + i) = (float4){0.f, 0.f, 0.f, 0.f};
}

// ---------------------------------------------------------------------------
// Per-head transpose + f32->bf16:  in (H, R, C) f32  ->  out (H, C, R) bf16.
// ---------------------------------------------------------------------------
__global__ __launch_bounds__(256) void transpose_w(const float* __restrict__ in,
                                                   bf16* __restrict__ out,
                                                   int R, int C) {
  __shared__ float tile[32][33];
  const int h = blockIdx.z;
  const int c0 = blockIdx.x * 32, r0 = blockIdx.y * 32;
  const int rr = threadIdx.x >> 3, cc = (threadIdx.x & 7) * 4;
  const float* ip = in + ((size_t)h * R + r0 + rr) * C + c0 + cc;
#pragma unroll
  for (int i = 0; i < 4; ++i) tile[rr][cc + i] = ip[i];
  __syncthreads();
  bf16* op = out + ((size_t)h * C + c0 + rr) * R + r0 + cc;
#pragma unroll
  for (int i = 0; i < 4; ++i) op[i] = __float2bfloat16(tile[cc + i][rr]);
}

// ---------------------------------------------------------------------------
// MFMA GEMM: C = A(MxK) @ BT^T (BT: N x K), bf16 in, fp32 accumulate.
// 128x128 tile, BK=64, 4 waves (64x64 quadrant each). LDS rows padded to 72.
// SPLIT-K via blockIdx.z. MODE 0: f32 C; MODE 1: bf16 C; MODE 2: bf16 C in
// (H,S,192) head-major; MODE 3: f32 partials at Cout + z*M*N; MODE 4: f32
// atomic-add into Cout (global_atomic_add_f32 via unsafeAtomicAdd; requires
// Cout pre-zeroed).
// ---------------------------------------------------------------------------
template<int MODE, int SPLIT = 1>
__global__ __launch_bounds__(256) void gemm_mfma(const bf16* __restrict__ A,
                                                 const bf16* __restrict__ BT,
                                                 void* __restrict__ Cout,
                                                 int M, int N, int K) {
  __shared__ bf16 As[128][72];
  __shared__ bf16 Bs[128][72];
  const int n0 = blockIdx.x * 128, m0 = blockIdx.y * 128;
  const int z  = (SPLIT > 1) ? blockIdx.z : 0;
  const int Ks = K / SPLIT;
  const int kbeg = z * Ks;
  const int tid = threadIdx.x;
  const int w = tid >> 6, l = tid & 63, lr = l & 15, lg = l >> 4;
  const int wr = w >> 1, wc = w & 1;

  f32x4 acc[4][4];
#pragma unroll
  for (int x = 0; x < 4; ++x)
#pragma unroll
    for (int y = 0; y < 4; ++y) acc[x][y] = (f32x4){0.f, 0.f, 0.f, 0.f};

  for (int kk = kbeg; kk < kbeg + Ks; kk += 64) {
#pragma unroll
    for (int i = 0; i < 4; ++i) {
      const int e = tid + 256 * i;
      const int r = e >> 3, k8 = (e & 7) * 8;
      *reinterpret_cast<bf16x8*>(&As[r][k8]) =
          ld8(A + (size_t)(m0 + r) * K + kk + k8);
      const int bn = (n0 + r < N) ? n0 + r : N - 1;
      *reinterpret_cast<bf16x8*>(&Bs[r][k8]) =
          ld8(BT + (size_t)bn * K + kk + k8);
    }
    __syncthreads();
#pragma unroll
    for (int kh = 0; kh < 2; ++kh) {
      bf16x8 af[4], bg[4];
#pragma unroll
      for (int x = 0; x < 4; ++x) af[x] = ld8(&As[wr * 64 + x * 16 + lr][kh * 32 + lg * 8]);
#pragma unroll
      for (int y = 0; y < 4; ++y) bg[y] = ld8(&Bs[wc * 64 + y * 16 + lr][kh * 32 + lg * 8]);
#pragma unroll
      for (int x = 0; x < 4; ++x)
#pragma unroll
        for (int y = 0; y < 4; ++y)
          acc[x][y] = __builtin_amdgcn_mfma_f32_16x16x32_bf16(af[x], bg[y], acc[x][y], 0, 0, 0);
    }
    __syncthreads();
  }

#pragma unroll
  for (int x = 0; x < 4; ++x) {
    const int mb = m0 + wr * 64 + x * 16 + lg * 4;
#pragma unroll
    for (int y = 0; y < 4; ++y) {
      const int n = n0 + wc * 64 + y * 16 + lr;
      if (n < N) {
#pragma unroll
        for (int i = 0; i < 4; ++i) {
          const int m = mb + i;
          if (MODE == 0) {
            ((float*)Cout)[(size_t)m * N + n] = acc[x][y][i];
          } else if (MODE == 1) {
            ((bf16*)Cout)[(size_t)m * N + n] = __float2bfloat16(acc[x][y][i]);
          } else if (MODE == 2) {
            const int h = n / QHEAD, j = n - h * QHEAD;
            ((bf16*)Cout)[((size_t)h * S_LEN + m) * QHEAD + j] = __float2bfloat16(acc[x][y][i]);
          } else if (MODE == 3) {
            ((float*)Cout)[(size_t)z * M * N + (size_t)m * N + n] = acc[x][y][i];
          } else {
            unsafeAtomicAdd(&((float*)Cout)[(size_t)m * N + n], acc[x][y][i]);
          }
        }
      }
    }
  }
}

// ---------------------------------------------------------------------------
// Fused 8-way split-K reduce + RMSNorm: part [8][S][QLORA] f32 -> bf16 out.
// ---------------------------------------------------------------------------
__global__ __launch_bounds__(256) void rmsnorm_fused(const float* __restrict__ part,
                                                     const float* __restrict__ w,
                                                     bf16* __restrict__ out) {
  const int row = blockIdx.x, tid = threadIdx.x;
  __shared__ float red[256];
  float x[6];
  float ss = 0.f;
#pragma unroll
  for (int j = 0; j < 6; ++j) {
    const int c = tid + 256 * j;
    float s = 0.f;
#pragma unroll
    for (int z = 0; z < 8; ++z) s += part[((size_t)z * S_LEN + row) * QLORA + c];
    x[j] = s; ss += s * s;
  }
  red[tid] = ss; __syncthreads();
  for (int t = 128; t > 0; t >>= 1) { if (tid < t) red[tid] += red[tid + t]; __syncthreads(); }
  const float rs = rsqrtf(red[0] / (float)QLORA + 1e-6f);
#pragma unroll
  for (int j = 0; j < 6; ++j) {
    const int c = tid + 256 * j;
    out[(size_t)row * QLORA + c] = __float2bfloat16(x[j] * rs * w[c]);
  }
}

// ---------------------------------------------------------------------------
// Fused 16-way split-K reduce + k_full build.
// ---------------------------------------------------------------------------
__global__ __launch_bounds__(256) void kfull_fused(const float* __restrict__ part,
                                                   const float* __restrict__ w,
                                                   const float* __restrict__ cosb,
                                                   const float* __restrict__ sinb,
                                                   bf16* __restrict__ kfull) {
  const int s = blockIdx.x, tid = threadIdx.x;
  __shared__ float red[256];
  float x0 = 0.f, x1 = 0.f;
#pragma unroll
  for (int z = 0; z < 16; ++z) {
    const float* row = part + ((size_t)z * S_LEN + s) * 576;
    x0 += row[tid]; x1 += row[256 + tid];
  }
  red[tid] = x0 * x0 + x1 * x1; __syncthreads();
  for (int t = 128; t > 0; t >>= 1) { if (tid < t) red[tid] += red[tid + t]; __syncthreads(); }
  const float rs = rsqrtf(red[0] / 512.f + 1e-6f);
  bf16* krow = kfull + (size_t)s * 576;
  krow[tid]       = __float2bfloat16(x0 * rs * w[tid]);
  krow[256 + tid] = __float2bfloat16(x1 * rs * w[256 + tid]);
  if (tid < 32) {
    const int j = tid;
    float a = 0.f, b = 0.f;
#pragma unroll
    for (int z = 0; z < 16; ++z) {
      const float* row = part + ((size_t)z * S_LEN + s) * 576;
      a += row[512 + j]; b += row[544 + j];
    }
    const float* cs = cosb + (size_t)s * 64;
    const float* sn = sinb + (size_t)s * 64;
    krow[512 + j] = __float2bfloat16(a * cs[j] - b * sn[j]);
    krow[544 + j] = __float2bfloat16(b * cs[32 + j] + a * sn[32 + j]);
  }
}

// ---------------------------------------------------------------------------
// RoPE on q_pe in-place in q_perm (H, S, 192) layout.
// ---------------------------------------------------------------------------
__global__ __launch_bounds__(256) void rope_q_kernel(bf16* __restrict__ qperm,
                                                     const float* __restrict__ cosb,
                                                     const float* __restrict__ sinb) {
  const int idx = blockIdx.x * 256 + threadIdx.x;   // H*S*32 total
  const int h = idx >> 15;
  const int rem = idx & 32767;
  const int s = rem >> 5;
  const int j = rem & 31;
  bf16* base = qperm + ((size_t)h * S_LEN + s) * QHEAD + NOPE_D;
  const float a = toF(base[j]), b = toF(base[32 + j]);
  const float* cs = cosb + (size_t)s * 64;
  const float* sn = sinb + (size_t)s * 64;
  base[j]      = __float2bfloat16(a * cs[j] - b * sn[j]);
  base[32 + j] = __float2bfloat16(b * cs[32 + j] + a * sn[32 + j]);
}

// ---------------------------------------------------------------------------
// latT (512 x 1024 bf16): latT[v][s] = kfull[s][v] (latent part only).
// ---------------------------------------------------------------------------
__global__ __launch_bounds__(256) void latT_kernel(const bf16* __restrict__ kfull,
                                                   bf16* __restrict__ latT) {
  const int gid = blockIdx.x * 256 + threadIdx.x;   // v*1024 + s
  const int v = gid >> 10, s = gid & 1023;
  latT[gid] = kfull[(size_t)s * 576 + v];
}

// ---------------------------------------------------------------------------
// Fused MLA flash attention (R6 structure). R10 changes:
//  (1) batch-issued B-operand loads PINNED with sched_barrier(0) so the
//      compiler cannot re-sink them (R5's intent, actually enforced now);
//      half-clusters (9+9 / 8+8) keep peak VGPR under the 168 cap.
//  (2) longest-job-first block order (qb = 31 - (y&31)) to shrink the
//      causal-imbalance makespan tail.
// ---------------------------------------------------------------------------
#define QB 32
__global__ __launch_bounds__(256, 3) void attn_mfma(const bf16* __restrict__ qperm,
                                                    const bf16* __restrict__ kfull,
                                                    const bf16* __restrict__ kcT,
                                                    const bf16* __restrict__ vcT,
                                                    const bf16* __restrict__ latT,
                                                    bf16* __restrict__ attnv,
                                                    float scale) {
  const int bi = blockIdx.x;            // 0..4095
  const int y  = bi >> 3;               // 0..511
  const int h  = (bi & 7) * 16 + (y >> 5);
  const int qb = 31 - (y & 31);         // longest-first within each head
  const int r0 = qb * QB;
  const int tid = threadIdx.x;
  const int w = tid >> 6, l = tid & 63, lr = l & 15, lg = l >> 4;

  __shared__ bf16  Qf[QB][584];
  __shared__ float St[QB][68];
  __shared__ bf16  Pt[QB][72];
  __shared__ float mrow[QB], lrow[QB], arow[QB];

  for (int e = tid; e < QB * 64; e += 256) {
    const int i = e >> 6, j = e & 63;
    Qf[i][512 + j] = qperm[((size_t)h * S_LEN + r0 + i) * QHEAD + NOPE_D + j];
  }
  {
    bf16x8 qn[2][4];
#pragma unroll
    for (int x = 0; x < 2; ++x) {
      const bf16* qp = qperm + ((size_t)h * S_LEN + r0 + x * 16 + lr) * QHEAD;
#pragma unroll
      for (int t = 0; t < 4; ++t) qn[x][t] = ld8(qp + t * 32 + lg * 8);
    }
#pragma unroll
    for (int ff = 0; ff < 2; ++ff) {
      bf16x8 kb[4][4];
#pragma unroll
      for (int f4 = 0; f4 < 4; ++f4) {
        const int col = w * 128 + (ff * 4 + f4) * 16 + lr;
        const bf16* kp = kcT + ((size_t)h * 512 + col) * 128 + lg * 8;
#pragma unroll
        for (int t = 0; t < 4; ++t) kb[f4][t] = ld8(kp + t * 32);
      }
      __builtin_amdgcn_sched_barrier(0);   // pin the 16 loads above
#pragma unroll
      for (int f4 = 0; f4 < 4; ++f4) {
        f32x4 a0 = {0.f, 0.f, 0.f, 0.f}, a1 = {0.f, 0.f, 0.f, 0.f};
        const int col = w * 128 + (ff * 4 + f4) * 16 + lr;
#pragma unroll
        for (int t = 0; t < 4; ++t) {
          a0 = __builtin_amdgcn_mfma_f32_16x16x32_bf16(qn[0][t], kb[f4][t], a0, 0, 0, 0);
          a1 = __builtin_amdgcn_mfma_f32_16x16x32_bf16(qn[1][t], kb[f4][t], a1, 0, 0, 0);
        }
#pragma unroll
        for (int i = 0; i < 4; ++i) {
          Qf[lg * 4 + i][col]      = __float2bfloat16(a0[i]);
          Qf[16 + lg * 4 + i][col] = __float2bfloat16(a1[i]);
        }
      }
    }
  }
  if (tid < QB) { mrow[tid] = -INFINITY; lrow[tid] = 0.f; }
  __syncthreads();

  f32x4 o[2][8];
#pragma unroll
  for (int x = 0; x < 2; ++x)
#pragma unroll
    for (int f = 0; f < 8; ++f) o[x][f] = (f32x4){0.f, 0.f, 0.f, 0.f};

  const int kend = r0 + QB;
  for (int k0 = 0; k0 < kend; k0 += 64) {
    // ---- phase A: scores; 18 B-loads in two pinned 9-clusters ----
    {
      const int key = k0 + w * 16 + lr;
      const bf16* kp = kfull + (size_t)key * 576 + lg * 8;
      f32x4 s0 = {0.f, 0.f, 0.f, 0.f}, s1 = {0.f, 0.f, 0.f, 0.f};
#pragma unroll
      for (int hh = 0; hh < 2; ++hh) {
        bf16x8 bb[9];
#pragma unroll
        for (int t = 0; t < 9; ++t) bb[t] = ld8(kp + (hh * 9 + t) * 32);
        __builtin_amdgcn_sched_barrier(0);   // loads may not sink past here
        __builtin_amdgcn_s_setprio(1);
#pragma unroll
        for (int t = 0; t < 9; ++t) {
          const int tt = hh * 9 + t;
          s0 = __builtin_amdgcn_mfma_f32_16x16x32_bf16(ld8(&Qf[lr][tt * 32 + lg * 8]), bb[t], s0, 0, 0, 0);
          s1 = __builtin_amdgcn_mfma_f32_16x16x32_bf16(ld8(&Qf[16 + lr][tt * 32 + lg * 8]), bb[t], s1, 0, 0, 0);
        }
        __builtin_amdgcn_s_setprio(0);
      }
#pragma unroll
      for (int i = 0; i < 4; ++i) {
        const int q0 = r0 + lg * 4 + i;
        const int q1 = r0 + 16 + lg * 4 + i;
        St[lg * 4 + i][w * 16 + lr]      = (key <= q0) ? s0[i] * scale : -INFINITY;
        St[16 + lg * 4 + i][w * 16 + lr] = (key <= q1) ? s1[i] * scale : -INFINITY;
      }
    }
    __syncthreads();
    // ---- phase B: online softmax; 8 threads per row ----
    {
      const int r = tid >> 3, seg = tid & 7;
      const float4 v0 = *reinterpret_cast<const float4*>(&St[r][seg * 8]);
      const float4 v1 = *reinterpret_cast<const float4*>(&St[r][seg * 8 + 4]);
      float mx = fmaxf(fmaxf(fmaxf(v0.x, v0.y), fmaxf(v0.z, v0.w)),
                       fmaxf(fmaxf(v1.x, v1.y), fmaxf(v1.z, v1.w)));
#pragma unroll
      for (int m = 1; m < 8; m <<= 1) mx = fmaxf(mx, __shfl_xor(mx, m, 64));
      const float mold = mrow[r];
      const float mnew = fmaxf(mold, mx);
      const float p0 = expf(v0.x - mnew), p1 = expf(v0.y - mnew);
      const float p2 = expf(v0.z - mnew), p3 = expf(v0.w - mnew);
      const float p4 = expf(v1.x - mnew), p5 = expf(v1.y - mnew);
      const float p6 = expf(v1.z - mnew), p7 = expf(v1.w - mnew);
      Pt[r][seg * 8 + 0] = __float2bfloat16(p0);
      Pt[r][seg * 8 + 1] = __float2bfloat16(p1);
      Pt[r][seg * 8 + 2] = __float2bfloat16(p2);
      Pt[r][seg * 8 + 3] = __float2bfloat16(p3);
      Pt[r][seg * 8 + 4] = __float2bfloat16(p4);
      Pt[r][seg * 8 + 5] = __float2bfloat16(p5);
      Pt[r][seg * 8 + 6] = __float2bfloat16(p6);
      Pt[r][seg * 8 + 7] = __float2bfloat16(p7);
      float sum = p0 + p1 + p2 + p3 + p4 + p5 + p6 + p7;
#pragma unroll
      for (int m = 1; m < 8; m <<= 1) sum += __shfl_xor(sum, m, 64);
      if (seg == 0) {
        const float alpha = expf(mold - mnew);
        lrow[r] = lrow[r] * alpha + sum;
        mrow[r] = mnew;
        arow[r] = alpha;
      }
    }
    __syncthreads();
    // ---- phase C: O = O*alpha + P @ latent; two pinned 8-load clusters ----
    {
      float al0[4], al1[4];
#pragma unroll
      for (int i = 0; i < 4; ++i) {
        al0[i] = arow[lg * 4 + i];
        al1[i] = arow[16 + lg * 4 + i];
      }
#pragma unroll
      for (int f = 0; f < 8; ++f)
#pragma unroll
        for (int i = 0; i < 4; ++i) {
          o[0][f][i] *= al0[i];
          o[1][f][i] *= al1[i];
        }
      bf16x8 pa[2][2];
      pa[0][0] = ld8(&Pt[lr][lg * 8]);
      pa[0][1] = ld8(&Pt[lr][32 + lg * 8]);
      pa[1][0] = ld8(&Pt[16 + lr][lg * 8]);
      pa[1][1] = ld8(&Pt[16 + lr][32 + lg * 8]);
#pragma unroll
      for (int hh = 0; hh < 2; ++hh) {
        bf16x8 bl[8];
#pragma unroll
        for (int f = 0; f < 4; ++f) {
          const int v = w * 128 + (hh * 4 + f) * 16 + lr;
          const bf16* bp = latT + (size_t)v * S_LEN + k0 + lg * 8;
          bl[2 * f]     = ld8(bp);
          bl[2 * f + 1] = ld8(bp + 32);
        }
        __builtin_amdgcn_sched_barrier(0);
        __builtin_amdgcn_s_setprio(1);
#pragma unroll
        for (int f = 0; f < 4; ++f) {
          const int fo = hh * 4 + f;
          o[0][fo] = __builtin_amdgcn_mfma_f32_16x16x32_bf16(pa[0][0], bl[2 * f],     o[0][fo], 0, 0, 0);
          o[0][fo] = __builtin_amdgcn_mfma_f32_16x16x32_bf16(pa[0][1], bl[2 * f + 1], o[0][fo], 0, 0, 0);
          o[1][fo] = __builtin_amdgcn_mfma_f32_16x16x32_bf16(pa[1][0], bl[2 * f],     o[1][fo], 0, 0, 0);
          o[1][fo] = __builtin_amdgcn_mfma_f32_16x16x32_bf16(pa[1][1], bl[2 * f + 1], o[1][fo], 0, 0, 0);
        }
        __builtin_amdgcn_s_setprio(0);
      }
    }
  }

  // ---- normalize, park O (bf16) in Qf[:, 0:512] ----
  {
    float li0[4], li1[4];
#pragma unroll
    for (int i = 0; i < 4; ++i) {
      li0[i] = 1.f / lrow[lg * 4 + i];
      li1[i] = 1.f / lrow[16 + lg * 4 + i];
    }
#pragma unroll
    for (int f = 0; f < 8; ++f) {
      const int v = w * 128 + f * 16 + lr;
#pragma unroll
      for (int i = 0; i < 4; ++i) {
        Qf[lg * 4 + i][v]      = __float2bfloat16(o[0][f][i] * li0[i]);
        Qf[16 + lg * 4 + i][v] = __float2bfloat16(o[1][f][i] * li1[i]);
      }
    }
  }
  __syncthreads();
  // ---- attn_v = O(32x512) @ vc_w[h](512x128); pinned 8-load clusters ----
#pragma unroll
  for (int cf = 0; cf < 2; ++cf) {
    const int c = w * 32 + cf * 16 + lr;
    const bf16* vp = vcT + ((size_t)h * 128 + c) * 512 + lg * 8;
    f32x4 acc0 = {0.f, 0.f, 0.f, 0.f}, acc1 = {0.f, 0.f, 0.f, 0.f};
#pragma unroll
    for (int hh = 0; hh < 2; ++hh) {
      bf16x8 vb[8];
#pragma unroll
      for (int kt = 0; kt < 8; ++kt) vb[kt] = ld8(vp + (hh * 8 + kt) * 32);
      __builtin_amdgcn_sched_barrier(0);
#pragma unroll
      for (int kt = 0; kt < 8; ++kt) {
        const int kk = hh * 8 + kt;
        acc0 = __builtin_amdgcn_mfma_f32_16x16x32_bf16(ld8(&Qf[lr][kk * 32 + lg * 8]), vb[kt], acc0, 0, 0, 0);
        acc1 = __builtin_amdgcn_mfma_f32_16x16x32_bf16(ld8(&Qf[16 + lr][kk * 32 + lg * 8]), vb[kt], acc1, 0, 0, 0);
      }
    }
#pragma unroll
    for (int i = 0; i < 4; ++i) {
      attnv[(size_t)(r0 + lg * 4 + i) * (NHEAD * VDIM_D) + h * VDIM_D + c]      = __float2bfloat16(acc0[i]);
      attnv[(size_t)(r0 + 16 + lg * 4 + i) * (NHEAD * VDIM_D) + h * VDIM_D + c] = __float2bfloat16(acc1[i]);
    }
  }
}

// ---------------------------------------------------------------------------
extern "C" void kernel_launch(void* const* d_in, const int* in_sizes, int n_in,
                              void* d_out, int out_size, void* d_ws, size_t ws_size,
                              hipStream_t stream) {
  const float* hidden    = (const float*)d_in[0];
  const float* cosb      = (const float*)d_in[1];
  const float* sinb      = (const float*)d_in[2];
  const float* q_a_w     = (const float*)d_in[3];
  const float* q_a_ln_w  = (const float*)d_in[4];
  const float* q_b_w     = (const float*)d_in[5];
  const float* kv_a_w    = (const float*)d_in[6];
  const float* kv_a_ln_w = (const float*)d_in[7];
  const float* kc_w      = (const float*)d_in[8];
  const float* vc_w      = (const float*)d_in[9];
  const float* o_w       = (const float*)d_in[10];
  float* out = (float*)d_out;

  // workspace layout (bytes), lifetime-overlapped; total 243,269,632 (~232 MiB).
  char* ws = (char*)d_ws;
  bf16*  attnv   = (bf16*)(ws + 0);            // 1024x16384 bf16  33,554,432
  bf16*  kcT     = (bf16*)(ws + 33554432);     // (H,512,128)bf16  16,777,216
  bf16*  vcT     = (bf16*)(ws + 50331648);     // (H,128,512)bf16  16,777,216
  bf16*  kfull   = (bf16*)(ws + 67108864);     // 1024x576   bf16   1,179,648
  bf16*  latT    = (bf16*)(ws + 68288512);     // 512x1024   bf16   1,048,576
  bf16*  qan     = (bf16*)(ws + 69337088);     // 1024x1536  bf16   3,145,728
  bf16*  hb      = (bf16*)(ws + 72482816);     // 1024x5120  bf16  10,485,760
  bf16*  qaT     = (bf16*)(ws + 82968576);     // 1536x5120  bf16  15,728,640
  bf16*  kvaT    = (bf16*)(ws + 98697216);     // 576x5120   bf16   5,898,240
  bf16*  qperm   = (bf16*)(ws + 104595456);    // (H,S,192)  bf16  50,331,648
  float* qa_part = (float*)(ws + 104595456);   // [8][1024][1536] f32 50,331,648 (pre-qperm)
  bf16*  qbT     = (bf16*)(ws + 154927104);    // 24576x1536 bf16  75,497,472
  float* kv_part = (float*)(ws + 154927104);   // [16][1024][576] f32 37,748,736 (post-q_b)
  bf16*  owT     = (bf16*)(ws + 75497472);     // 5120x16384 bf16 167,772,160 (post-attn)

  const double msc = 0.1 * log(40.0) + 1.0;
  const float scale = (float)(pow((double)QHEAD, -0.5) * msc * msc);

  // hidden -> bf16
  cvt_bf16<<<(S_LEN * DMODEL) / 1024, 256, 0, stream>>>(hidden, hb);
  // weight transposes -> bf16
  transpose_w<<<dim3(QLORA / 32, DMODEL / 32, 1), 256, 0, stream>>>(q_a_w, qaT, DMODEL, QLORA);
  transpose_w<<<dim3(576 / 32, DMODEL / 32, 1), 256, 0, stream>>>(kv_a_w, kvaT, DMODEL, 576);
  transpose_w<<<dim3((NHEAD * QHEAD) / 32, QLORA / 32, 1), 256, 0, stream>>>(q_b_w, qbT, QLORA, NHEAD * QHEAD);
  transpose_w<<<dim3(512 / 32, 128 / 32, NHEAD), 256, 0, stream>>>(kc_w, kcT, 128, 512);
  transpose_w<<<dim3(128 / 32, 512 / 32, NHEAD), 256, 0, stream>>>(vc_w, vcT, 512, 128);

  // q_a: (1024x5120)@(5120x1536), split-K 8 -> qa_part
  gemm_mfma<3, 8><<<dim3(QLORA / 128, S_LEN / 128, 8), 256, 0, stream>>>(
      hb, qaT, qa_part, S_LEN, QLORA, DMODEL);
  // fused reduce + rmsnorm -> qan
  rmsnorm_fused<<<S_LEN, 256, 0, stream>>>(qa_part, q_a_ln_w, qan);
  // q_b: (1024x1536)@(1536x24576) -> qperm (head-major)
  gemm_mfma<2><<<dim3((NHEAD * QHEAD) / 128, S_LEN / 128), 256, 0, stream>>>(
      qan, qbT, qperm, S_LEN, NHEAD * QHEAD, QLORA);
  // kv_a: (1024x5120)@(5120x576), split-K 16 -> kv_part
  gemm_mfma<3, 16><<<dim3(5, S_LEN / 128, 16), 256, 0, stream>>>(
      hb, kvaT, kv_part, S_LEN, KVLORA + ROPE_D, DMODEL);
  // fused reduce + k_full build
  kfull_fused<<<S_LEN, 256, 0, stream>>>(kv_part, kv_a_ln_w, cosb, sinb, kfull);
  // latent transpose for PV B-operands
  latT_kernel<<<(KVLORA * S_LEN) / 256, 256, 0, stream>>>(kfull, latT);
  // rope q_pe in place
  rope_q_kernel<<<(NHEAD * S_LEN * 32) / 256, 256, 0, stream>>>(qperm, cosb, sinb);
  // fused MFMA attention (q absorb + flash + vc projection), XCD-swizzled
  attn_mfma<<<dim3(NHEAD * (S_LEN / QB)), 256, 0, stream>>>(
      qperm, kfull, kcT, vcT, latT, attnv, scale);
  // o_w transpose (pre-attn buffers now dead; owT overlaps them)
  transpose_w<<<dim3(DMODEL / 32, (NHEAD * VDIM_D) / 32, 1), 256, 0, stream>>>(
      o_w, owT, NHEAD * VDIM_D, DMODEL);
  // zero out, then output projection with split-K 4 atomic accumulation:
  // (1024x16384)@(16384x5120) -> out (f32)
  zero_f32<<<(S_LEN * DMODEL) / 1024, 256, 0, stream>>>(out);
  gemm_mfma<4, 4><<<dim3(DMODEL / 128, S_LEN / 128, 4), 256, 0, stream>>>(
      attnv, owT, out, S_LEN, DMODEL, NHEAD * VDIM_D);
}